// Round 4
// baseline (198.181 us; speedup 1.0000x reference)
//
#include <hip/hip_runtime.h>
#include <hip/hip_bf16.h>

// MHA: B=2, S=4096, E=512, H=8, D=64. fp32 in/out, bf16 MFMA internally.
// ws (shorts): XB/O [8192*512] | WB [4*512*512] | Q | K | VT
// Q pre-scaled by log2(e)/sqrt(D). attn computes S^T = mfma(K,Q) with a
// PERMUTED K-row map: within a wave's 32-t slice, tile T row m holds
// t = 8*(m>>2) + 4*T + (m&3), so the S^T C-layout across the (T0,T1) pair
// IS the 16x16x32 A-frag layout -> PV runs on full-rate 16x16x32 MFMA.
// R4: waves partition over T, not Q. Block = 64 q-rows (shared by all 4
// waves, Q in regs), 128-t staged dbuf; wave w computes t-slice w*32..+32
// for ALL 64 q. R3's bK/bv LDS frags were wave-invariant (4x redundant
// reads); now each wave reads its own slice -> LDS read traffic /4
// (8 b128/wave/iter), and wave count doubles to 4096 (grid 16x64).
// Partial O/psum per wave are additive (no running max) -> end-of-kernel
// cross-wave fp32 reduce through LDS (aliases staging buffers).
// psum via ones-vector MFMA: lane holds row-sum replicated over l16.
// K LDS swizzle f(r) = (r&7)^((r>>2)&7); V chunk swizzle c ^= (r&7).
// truncating bf16 P-pack; numerator & denominator share truncated P.

typedef __attribute__((ext_vector_type(8))) short short8;
typedef __attribute__((ext_vector_type(4))) short short4v;
typedef __attribute__((ext_vector_type(4))) float floatx4;
typedef __attribute__((ext_vector_type(2))) float floatx2;

#define SEQ 4096
#define EMB 512
#define NH 8
#define HD 64
#define MROWS 8192
#define SC2 0.18033688011112042f  // log2(e)/sqrt(64)

__device__ inline unsigned short f2bf_rne(float f) {
    union { float f; unsigned int u; } c; c.f = f;
    unsigned int u = c.u;
    return (unsigned short)((u + 0x7FFFu + ((u >> 16) & 1u)) >> 16);
}

__device__ inline short8 load8f(const float* __restrict__ p) {
    float4 a = *(const float4*)p;
    float4 b = *(const float4*)(p + 4);
    short8 r;
    r[0] = (short)f2bf_rne(a.x); r[1] = (short)f2bf_rne(a.y);
    r[2] = (short)f2bf_rne(a.z); r[3] = (short)f2bf_rne(a.w);
    r[4] = (short)f2bf_rne(b.x); r[5] = (short)f2bf_rne(b.y);
    r[6] = (short)f2bf_rne(b.z); r[7] = (short)f2bf_rne(b.w);
    return r;
}

__device__ inline void gload_lds16(const unsigned short* g, unsigned short* l) {
    __builtin_amdgcn_global_load_lds(
        (__attribute__((address_space(1))) void*)(void*)g,
        (__attribute__((address_space(3))) void*)l,
        16, 0, 0);
}

// pack 2 f32 -> 2 bf16, round-half-up (epilogue-quality)
__device__ inline unsigned int pk_bf2(float a, float b) {
    union { float f; unsigned int u; } ca, cb; ca.f = a; cb.f = b;
    return __builtin_amdgcn_perm(cb.u + 0x8000u, ca.u + 0x8000u, 0x07060302u);
}

// pack 2 f32 -> 2 bf16, truncating (P-matrix: positive values, <=0.2% bias)
__device__ inline unsigned int pk_bf2t(float a, float b) {
    union { float f; unsigned int u; } ca, cb; ca.f = a; cb.f = b;
    return __builtin_amdgcn_perm(cb.u, ca.u, 0x07060302u);
}

// ---------------- fp32 -> bf16 pre-convert ----------------
__global__ __launch_bounds__(256) void convert_kernel(
    const float* __restrict__ x, const float* __restrict__ Wq,
    const float* __restrict__ Wk, const float* __restrict__ Wv,
    const float* __restrict__ Wo, unsigned short* __restrict__ xb,
    unsigned short* __restrict__ wb)
{
    const size_t i8 = ((size_t)blockIdx.x * 256 + threadIdx.x) * 8;
    const float* src; unsigned short* dst;
    if (i8 < (size_t)MROWS * EMB) { src = x + i8; dst = xb + i8; }
    else {
        size_t j = i8 - (size_t)MROWS * EMB;
        int w = (int)(j >> 18); size_t off = j & 262143;
        src = (w == 0 ? Wq : w == 1 ? Wk : w == 2 ? Wv : Wo) + off;
        dst = wb + (size_t)w * 262144 + off;
    }
    *(short8*)dst = load8f(src);
}

// ---------------- QKV projection, 128x128, BK=64, dbuf, LDS epilogue ----------------
// z=0 -> Q [b,h,s,d] scaled SC2; z=1 -> K [b,h,s,d]; z=2 -> V^T [b,h,d,s]
__global__ __launch_bounds__(256) void qkv_kernel(
    const unsigned short* __restrict__ xb, const unsigned short* __restrict__ wb,
    const float* __restrict__ bq, const float* __restrict__ bk,
    const float* __restrict__ bv, unsigned short* __restrict__ Qo,
    unsigned short* __restrict__ Ko, unsigned short* __restrict__ VTo)
{
    __shared__ unsigned short smem[32768];  // sA[2][8192] | sB[2][8192]; epilogue ct aliases

    const int tid = threadIdx.x, wave = tid >> 6, lane = tid & 63;
    const int quad = lane >> 4, l16 = lane & 15;
    const int wm = wave >> 1, wn = wave & 1;
    const int row0 = blockIdx.x * 128, col0 = blockIdx.y * 128;
    const int z = blockIdx.z;

    unsigned short* sA = smem;
    unsigned short* sB = smem + 16384;

    const unsigned short* A = xb + (size_t)row0 * EMB;
    const unsigned short* Bm = wb + (size_t)z * 262144 + (size_t)col0 * EMB;
    const float* bias = z == 0 ? bq : z == 1 ? bk : bv;
    unsigned short* out = z == 0 ? Qo : z == 1 ? Ko : VTo;

    auto stage = [&](int buf, int k0) {
#pragma unroll
        for (int it = 0; it < 4; ++it) {
            const int s = it * 256 + tid;
            const int row = s >> 3, cg = (s & 7) ^ (row & 7);
            const size_t go = (size_t)row * EMB + k0 + cg * 8;
            gload_lds16(A + go, &sA[buf * 8192 + (it * 256 + wave * 64) * 8]);
            gload_lds16(Bm + go, &sB[buf * 8192 + (it * 256 + wave * 64) * 8]);
        }
    };

    floatx4 acc[4][4];
#pragma unroll
    for (int i = 0; i < 4; ++i)
#pragma unroll
        for (int j = 0; j < 4; ++j) { floatx4 zz = {0.f,0.f,0.f,0.f}; acc[i][j] = zz; }

    stage(0, 0);
    int buf = 0;
    for (int k0 = 0; k0 < EMB; k0 += 64) {
        __syncthreads();
        if (k0 + 64 < EMB) stage(buf ^ 1, k0 + 64);
#pragma unroll
        for (int kk = 0; kk < 2; ++kk) {
            short8 a[4], b[4];
#pragma unroll
            for (int mi = 0; mi < 4; ++mi)
                a[mi] = *(const short8*)&sA[buf * 8192 + (wm * 64 + mi * 16 + l16) * 64 + (((kk * 4 + quad) ^ (l16 & 7)) << 3)];
#pragma unroll
            for (int ni = 0; ni < 4; ++ni)
                b[ni] = *(const short8*)&sB[buf * 8192 + (wn * 64 + ni * 16 + l16) * 64 + (((kk * 4 + quad) ^ (l16 & 7)) << 3)];
            if (z != 2) {
                // swapped operands -> acc[i][j] = C^T block: rows n (i), cols m (j)
#pragma unroll
                for (int i = 0; i < 4; ++i)
#pragma unroll
                    for (int j = 0; j < 4; ++j)
                        acc[i][j] = __builtin_amdgcn_mfma_f32_16x16x32_bf16(b[i], a[j], acc[i][j], 0, 0, 0);
            } else {
#pragma unroll
                for (int i = 0; i < 4; ++i)
#pragma unroll
                    for (int j = 0; j < 4; ++j)
                        acc[i][j] = __builtin_amdgcn_mfma_f32_16x16x32_bf16(a[i], b[j], acc[i][j], 0, 0, 0);
            }
        }
        buf ^= 1;
    }

    // ---- epilogue: pack b64 into ct[row][132] then coalesced b128 stores ----
    __syncthreads();
    unsigned short* ct = smem;  // 128 x 132 shorts = 33.8 KB (aliases staging)
    const float qs = (z == 0) ? SC2 : 1.0f;
    if (z != 2) {
#pragma unroll
        for (int i = 0; i < 4; ++i) {
            const int n0 = wn * 64 + i * 16 + quad * 4;
            const float4 fb = *(const float4*)&bias[col0 + n0];
#pragma unroll
            for (int j = 0; j < 4; ++j) {
                const int m = wm * 64 + j * 16 + l16;
                ushort4 pk;
                pk.x = f2bf_rne((acc[i][j][0] + fb.x) * qs);
                pk.y = f2bf_rne((acc[i][j][1] + fb.y) * qs);
                pk.z = f2bf_rne((acc[i][j][2] + fb.z) * qs);
                pk.w = f2bf_rne((acc[i][j][3] + fb.w) * qs);
                *(ushort4*)&ct[m * 132 + n0] = pk;
            }
        }
    } else {
#pragma unroll
        for (int j = 0; j < 4; ++j) {
            const int n = wn * 64 + j * 16 + l16;
            const float fb = bias[col0 + n];
#pragma unroll
            for (int i = 0; i < 4; ++i) {
                const int m0 = wm * 64 + i * 16 + quad * 4;
                ushort4 pk;
                pk.x = f2bf_rne(acc[i][j][0] + fb);
                pk.y = f2bf_rne(acc[i][j][1] + fb);
                pk.z = f2bf_rne(acc[i][j][2] + fb);
                pk.w = f2bf_rne(acc[i][j][3] + fb);
                *(ushort4*)&ct[n * 132 + m0] = pk;
            }
        }
    }
    __syncthreads();
#pragma unroll
    for (int it = 0; it < 8; ++it) {
        const int idx = it * 256 + tid;
        const int row = idx >> 4, chunk = idx & 15;
        short8 v = *(const short8*)&ct[row * 132 + chunk * 8];
        size_t addr;
        if (z != 2) {
            const int m_g = row0 + row;
            const int b = m_g >> 12, s = m_g & 4095;
            const int n_g = col0 + chunk * 8;
            const int h = n_g >> 6, d = n_g & 63;
            addr = ((size_t)((b * NH + h) * SEQ + s)) * HD + d;
        } else {
            const int n_g = col0 + row;
            const int h = n_g >> 6, d = n_g & 63;
            const int m_g = row0 + chunk * 8;
            const int b = m_g >> 12, s0 = m_g & 4095;
            addr = ((size_t)((b * NH + h) * HD + d)) * SEQ + s0;
        }
        *(short8*)&out[addr] = v;
    }
}

// ---------------- flash attention: t-sliced waves, 64 q/block, K=32 PV ----------------
// grid (bh, q-tile): blockId = x + 16*y -> XCD = x&7 for ALL q-tiles of a bh
// -> each XCD serves 2 bh's K/V (4MB, fits its L2).
__global__ __launch_bounds__(256, 2) void attn_kernel(
    const unsigned short* __restrict__ Q, const unsigned short* __restrict__ K,
    const unsigned short* __restrict__ VT, unsigned short* __restrict__ Oout)
{
    // staging: [buf][ sK 128t x 64d (8192) | sVT 64d x 128t (8192) ]
    // reduction phase aliases as float: [w][q 0..63][34] (padded rows)
    __shared__ unsigned short smem[32768];
    __shared__ float sPS[256];  // [w][q] psum partials

    const int tid = threadIdx.x, wave = tid >> 6, lane = tid & 63;
    const int quad = lane >> 4, l16 = lane & 15;
    const int bh = blockIdx.x, q0 = blockIdx.y * 64;
    const int xm = l16 & 7;

    const unsigned short* Qh = Q + (size_t)bh * SEQ * HD;
    const unsigned short* Kh = K + (size_t)bh * SEQ * HD;
    const unsigned short* Vh = VT + (size_t)bh * HD * SEQ;

    // all waves hold the SAME 64 q-rows in regs (4 tiles of 16)
    short8 qf[4][2];  // [mi][kk]
#pragma unroll
    for (int mi = 0; mi < 4; ++mi)
#pragma unroll
        for (int kk = 0; kk < 2; ++kk)
            qf[mi][kk] = *(const short8*)(Qh + (size_t)(q0 + mi * 16 + l16) * HD + kk * 32 + quad * 8);

    // permuted K-row map within this wave's 32-t slice: tile T, A-row m ->
    // t = wave*32 + 8*(m>>2) + 4*T + (m&3); output rows (quad,r) hold
    // t = wave*32 + 8*quad + 4*T + r -> (T0,T1) pair = 16x16x32 A-frag.
    int kbase[2], kx0[2], kx1[2];
#pragma unroll
    for (int T = 0; T < 2; ++T) {
        const int R = wave * 32 + ((l16 >> 2) << 3) + (T << 2) + (l16 & 3);
        const int fR = (R & 7) ^ ((R >> 2) & 7);  // matches staging swizzle fK
        kbase[T] = R * 64;
        kx0[T] = (quad ^ fR) << 3;
        kx1[T] = ((4 + quad) ^ fR) << 3;
    }

    floatx4 oacc[4][4];  // [mi][dt] partial O over this wave's t-slices
#pragma unroll
    for (int mi = 0; mi < 4; ++mi)
#pragma unroll
        for (int dt = 0; dt < 4; ++dt) { floatx4 zz = {0.f,0.f,0.f,0.f}; oacc[mi][dt] = zz; }
    floatx4 sacc[4];  // psum partial via ones-MFMA (row-sum, replicated over l16)
#pragma unroll
    for (int mi = 0; mi < 4; ++mi) { floatx4 zz = {0.f,0.f,0.f,0.f}; sacc[mi] = zz; }
    const floatx4 z4 = {0.f, 0.f, 0.f, 0.f};
    const short ob = (short)0x3F80;  // bf16 1.0
    const short8 ones8 = {ob, ob, ob, ob, ob, ob, ob, ob};

    // stage 128 t into buffer `buf`: K 128x8 chunks, V 64x16 chunks
    auto stage = [&](int buf, int t0) {
        unsigned short* sK  = &smem[buf * 16384];
        unsigned short* sVT = &smem[buf * 16384 + 8192];
#pragma unroll
        for (int it = 0; it < 4; ++it) {
            const int s = it * 256 + tid;
            const int rK = s >> 3, jK = s & 7;
            const int cK = jK ^ ((rK & 7) ^ ((rK >> 2) & 7));
            gload_lds16(Kh + (size_t)(t0 + rK) * HD + cK * 8, &sK[(it * 256 + wave * 64) * 8]);
            const int rV = s >> 4, jV = s & 15;
            const int cV = jV ^ (rV & 7);
            gload_lds16(Vh + (size_t)rV * SEQ + t0 + cV * 8, &sVT[(it * 256 + wave * 64) * 8]);
        }
    };

    stage(0, 0);
    int buf = 0;
    for (int t0 = 0; t0 < SEQ; t0 += 128) {
        __syncthreads();
        if (t0 + 128 < SEQ) stage(buf ^ 1, t0 + 128);

        const unsigned short* sKs  = &smem[buf * 16384];
        const unsigned short* sVTs = &smem[buf * 16384 + 8192];

        // K frags for this wave's 32-t slice (4 b128)
        short8 bK0[2], bK1[2];
#pragma unroll
        for (int T = 0; T < 2; ++T) {
            bK0[T] = *(const short8*)&sKs[kbase[T] + kx0[T]];
            bK1[T] = *(const short8*)&sKs[kbase[T] + kx1[T]];
        }
        // V frags: chunk group = this wave's 32 t of the 128-t row (4 b128)
        short8 bv8[4];
#pragma unroll
        for (int dt = 0; dt < 4; ++dt)
            bv8[dt] = *(const short8*)&sVTs[(dt * 16 + l16) * 128 + (((wave * 4 + quad) ^ xm) << 3)];

#pragma unroll
        for (int mi = 0; mi < 4; ++mi) {
            // S^T = K Q^T (Q pre-scaled, log2-domain); const-zero C on kk=0
            floatx4 s0 = __builtin_amdgcn_mfma_f32_16x16x32_bf16(bK0[0], qf[mi][0], z4, 0, 0, 0);
            floatx4 s1 = __builtin_amdgcn_mfma_f32_16x16x32_bf16(bK0[1], qf[mi][0], z4, 0, 0, 0);
            s0 = __builtin_amdgcn_mfma_f32_16x16x32_bf16(bK1[0], qf[mi][1], s0, 0, 0, 0);
            s1 = __builtin_amdgcn_mfma_f32_16x16x32_bf16(bK1[1], qf[mi][1], s1, 0, 0, 0);

            // exp2 -> truncating pack; order [T0.r0-3, T1.r0-3] == k = 8*quad+0..7
            float e0 = __builtin_amdgcn_exp2f(s0[0]);
            float e1 = __builtin_amdgcn_exp2f(s0[1]);
            float e2 = __builtin_amdgcn_exp2f(s0[2]);
            float e3 = __builtin_amdgcn_exp2f(s0[3]);
            float e4 = __builtin_amdgcn_exp2f(s1[0]);
            float e5 = __builtin_amdgcn_exp2f(s1[1]);
            float e6 = __builtin_amdgcn_exp2f(s1[2]);
            float e7 = __builtin_amdgcn_exp2f(s1[3]);
            union { uint4 u; short8 s; } cv;
            cv.u.x = pk_bf2t(e0, e1);
            cv.u.y = pk_bf2t(e2, e3);
            cv.u.z = pk_bf2t(e4, e5);
            cv.u.w = pk_bf2t(e6, e7);
            const short8 paf = cv.s;

            sacc[mi] = __builtin_amdgcn_mfma_f32_16x16x32_bf16(paf, ones8, sacc[mi], 0, 0, 0);
#pragma unroll
            for (int dt = 0; dt < 4; ++dt)
                oacc[mi][dt] = __builtin_amdgcn_mfma_f32_16x16x32_bf16(paf, bv8[dt], oacc[mi][dt], 0, 0, 0);
        }
        buf ^= 1;
    }

    // ---- cross-wave reduction: O = sum_w O_w, psum = sum_w psum_w ----
    // psum partials (replicated over l16 -> 4 lanes/wave write)
    if (l16 == 0) {
#pragma unroll
        for (int mi = 0; mi < 4; ++mi)
#pragma unroll
            for (int r = 0; r < 4; ++r)
                sPS[wave * 64 + mi * 16 + quad * 4 + r] = sacc[mi][r];
    }

    float* sRed = (float*)smem;  // [w][q 0..63][34] (pad 34 breaks bank alias)
    const int b = bh >> 3, h = bh & 7;
    const int qr = wave * 16 + l16;  // this lane's output q-row (reduce phase)

#pragma unroll
    for (int hh = 0; hh < 2; ++hh) {
        __syncthreads();  // staging/prev-round reads done; also orders sPS
        // write this wave's partial for d-half hh
#pragma unroll
        for (int mi = 0; mi < 4; ++mi)
#pragma unroll
            for (int dd = 0; dd < 2; ++dd)
#pragma unroll
                for (int r = 0; r < 4; ++r)
                    sRed[wave * 2176 + (mi * 16 + quad * 4 + r) * 34 + dd * 16 + l16] =
                        oacc[mi][hh * 2 + dd][r];
        __syncthreads();
        // lane sums q-row qr, d-octet quad*8 across the 4 wave-partials
        floatx2 o8[4] = {{0.f,0.f},{0.f,0.f},{0.f,0.f},{0.f,0.f}};
#pragma unroll
        for (int w2 = 0; w2 < 4; ++w2) {
            const float* base = &sRed[w2 * 2176 + qr * 34 + quad * 8];
#pragma unroll
            for (int p = 0; p < 4; ++p) {
                floatx2 v = *(const floatx2*)(base + p * 2);
                o8[p] += v;
            }
        }
        const float pst = sPS[qr] + sPS[64 + qr] + sPS[128 + qr] + sPS[192 + qr];
        const float inv = 1.0f / pst;
        union { uint4 u; short8 s; } pk;
        pk.u.x = pk_bf2(o8[0][0] * inv, o8[0][1] * inv);
        pk.u.y = pk_bf2(o8[1][0] * inv, o8[1][1] * inv);
        pk.u.z = pk_bf2(o8[2][0] * inv, o8[2][1] * inv);
        pk.u.w = pk_bf2(o8[3][0] * inv, o8[3][1] * inv);
        const size_t addr = ((size_t)b * SEQ + q0 + qr) * EMB + h * HD + hh * 32 + quad * 8;
        *(short8*)&Oout[addr] = pk.s;
    }
}

// ---------------- output projection, 64x128 tile, double-buffered ----------------
__global__ __launch_bounds__(256) void outproj_kernel(
    const unsigned short* __restrict__ Ain, const unsigned short* __restrict__ wob,
    const float* __restrict__ bias, const float* __restrict__ X,
    float* __restrict__ out)
{
    __shared__ unsigned short sA[2][4096];
    __shared__ unsigned short sB[2][8192];

    const int tid = threadIdx.x, wave = tid >> 6, lane = tid & 63;
    const int quad = lane >> 4, l16 = lane & 15;
    const int wm = wave >> 1, wn = wave & 1;
    const int row0 = blockIdx.x * 64, col0 = blockIdx.y * 128;

    const unsigned short* A = Ain + (size_t)row0 * EMB;
    const unsigned short* Bm = wob + (size_t)col0 * EMB;

    auto stage = [&](int buf, int k0) {
#pragma unroll
        for (int it = 0; it < 2; ++it) {
            const int s = it * 256 + tid;
            const int row = s >> 3, cg = (s & 7) ^ (row & 7);
            gload_lds16(A + (size_t)row * EMB + k0 + cg * 8, &sA[buf][(it * 256 + wave * 64) * 8]);
        }
#pragma unroll
        for (int it = 0; it < 4; ++it) {
            const int s = it * 256 + tid;
            const int row = s >> 3, cg = (s & 7) ^ (row & 7);
            gload_lds16(Bm + (size_t)row * EMB + k0 + cg * 8, &sB[buf][(it * 256 + wave * 64) * 8]);
        }
    };

    floatx4 acc[2][4];
#pragma unroll
    for (int mi = 0; mi < 2; ++mi)
#pragma unroll
        for (int ni = 0; ni < 4; ++ni) { floatx4 zz = {0.f,0.f,0.f,0.f}; acc[mi][ni] = zz; }

    stage(0, 0);
    int buf = 0;
    for (int k0 = 0; k0 < EMB; k0 += 64) {
        __syncthreads();
        if (k0 + 64 < EMB) stage(buf ^ 1, k0 + 64);
#pragma unroll
        for (int kk = 0; kk < 2; ++kk) {
            short8 a[2], b[4];
#pragma unroll
            for (int mi = 0; mi < 2; ++mi)
                a[mi] = *(const short8*)&sA[buf][(wm * 32 + mi * 16 + l16) * 64 + (((kk * 4 + quad) ^ (l16 & 7)) << 3)];
#pragma unroll
            for (int ni = 0; ni < 4; ++ni)
                b[ni] = *(const short8*)&sB[buf][(wn * 64 + ni * 16 + l16) * 64 + (((kk * 4 + quad) ^ (l16 & 7)) << 3)];
#pragma unroll
            for (int mi = 0; mi < 2; ++mi)
#pragma unroll
                for (int ni = 0; ni < 4; ++ni)
                    acc[mi][ni] = __builtin_amdgcn_mfma_f32_16x16x32_bf16(a[mi], b[ni], acc[mi][ni], 0, 0, 0);
        }
        buf ^= 1;
    }

#pragma unroll
    for (int mi = 0; mi < 2; ++mi)
#pragma unroll
        for (int ni = 0; ni < 4; ++ni) {
            const int n = col0 + wn * 64 + ni * 16 + l16;
            const float bs = bias[n];
#pragma unroll
            for (int r = 0; r < 4; ++r) {
                const int m = row0 + wm * 32 + mi * 16 + quad * 4 + r;
                const size_t idx = (size_t)m * EMB + n;
                out[idx] = acc[mi][ni][r] + bs + X[idx];
            }
        }
}

extern "C" void kernel_launch(void* const* d_in, const int* in_sizes, int n_in,
                              void* d_out, int out_size, void* d_ws, size_t ws_size,
                              hipStream_t stream) {
    const float* x  = (const float*)d_in[0];
    const float* Wq = (const float*)d_in[1];
    const float* bq = (const float*)d_in[2];
    const float* Wk = (const float*)d_in[3];
    const float* bk = (const float*)d_in[4];
    const float* Wv = (const float*)d_in[5];
    const float* bv = (const float*)d_in[6];
    const float* Wo = (const float*)d_in[7];
    const float* bo = (const float*)d_in[8];
    float* out = (float*)d_out;

    const size_t SZ = (size_t)MROWS * EMB;
    unsigned short* wsXB = (unsigned short*)d_ws;  // also O (attn output)
    unsigned short* wsWB = wsXB + SZ;
    unsigned short* wsQ  = wsWB + 4 * 262144;
    unsigned short* wsK  = wsQ + SZ;
    unsigned short* wsVT = wsK + SZ;

    convert_kernel<<<2560, 256, 0, stream>>>(x, Wq, Wk, Wv, Wo, wsXB, wsWB);
    qkv_kernel<<<dim3(MROWS / 128, EMB / 128, 3), 256, 0, stream>>>(
        wsXB, wsWB, bq, bk, bv, wsQ, wsK, wsVT);
    attn_kernel<<<dim3(2 * NH, SEQ / 64), 256, 0, stream>>>(wsQ, wsK, wsVT, wsXB);
    outproj_kernel<<<dim3(MROWS / 64, EMB / 128), 256, 0, stream>>>(
        wsXB, wsWB + 3 * 262144, bo, x, out);
}

// Round 5
// 191.140 us; speedup vs baseline: 1.0368x; 1.0368x over previous
//
#include <hip/hip_runtime.h>
#include <hip/hip_bf16.h>

// MHA: B=2, S=4096, E=512, H=8, D=64. fp32 in/out, bf16 MFMA internally.
// ws (shorts): XB/O [8192*512] | WB [4*512*512] | Q | K | VT
// Q pre-scaled by log2(e)/sqrt(D). attn computes S^T = mfma(K,Q) with a
// PERMUTED K-row map: within a wave's 32-t slice, tile T row m holds
// t = wt*32 + 8*(m>>2) + 4*T + (m&3), so the S^T C-layout across the
// (T0,T1) pair IS the 16x16x32 A-frag layout -> full-rate K=32 PV.
// R5 = R3 with the g-loop (two 32-t halves) distributed over waves:
// 4 waves = 2 q-groups (wq) x 2 t-halves (wt). Each wave owns W_q=64 q
// (mi=0..3) x its 32-t half of every staged 64-t tile. LDS fragment
// addresses are IDENTICAL to R3 with g:=wt (proven 0-conflict), but
// per-CU ds_read count halves (reads amortize as 1/W_q; R4 lesson),
// while T_stage=64 keeps LDS at 32KB so waves/CU stay 8 (R4's 128-t
// staging blew the 64KB budget and never gained occupancy).
// Cross-wave (wt) O/psum fp32 reduce at end aliases staging (one-time).
// psum via ones-vector MFMA: lane holds row-sum replicated over l16.
// K LDS swizzle f(r) = (r&7)^((r>>2)&7); V chunk swizzle c ^= (r&7).
// truncating bf16 P-pack; numerator & denominator share truncated P.

typedef __attribute__((ext_vector_type(8))) short short8;
typedef __attribute__((ext_vector_type(4))) short short4v;
typedef __attribute__((ext_vector_type(4))) float floatx4;
typedef __attribute__((ext_vector_type(2))) float floatx2;

#define SEQ 4096
#define EMB 512
#define NH 8
#define HD 64
#define MROWS 8192
#define SC2 0.18033688011112042f  // log2(e)/sqrt(64)

__device__ inline unsigned short f2bf_rne(float f) {
    union { float f; unsigned int u; } c; c.f = f;
    unsigned int u = c.u;
    return (unsigned short)((u + 0x7FFFu + ((u >> 16) & 1u)) >> 16);
}

__device__ inline short8 load8f(const float* __restrict__ p) {
    float4 a = *(const float4*)p;
    float4 b = *(const float4*)(p + 4);
    short8 r;
    r[0] = (short)f2bf_rne(a.x); r[1] = (short)f2bf_rne(a.y);
    r[2] = (short)f2bf_rne(a.z); r[3] = (short)f2bf_rne(a.w);
    r[4] = (short)f2bf_rne(b.x); r[5] = (short)f2bf_rne(b.y);
    r[6] = (short)f2bf_rne(b.z); r[7] = (short)f2bf_rne(b.w);
    return r;
}

__device__ inline void gload_lds16(const unsigned short* g, unsigned short* l) {
    __builtin_amdgcn_global_load_lds(
        (__attribute__((address_space(1))) void*)(void*)g,
        (__attribute__((address_space(3))) void*)l,
        16, 0, 0);
}

// pack 2 f32 -> 2 bf16, round-half-up (epilogue-quality)
__device__ inline unsigned int pk_bf2(float a, float b) {
    union { float f; unsigned int u; } ca, cb; ca.f = a; cb.f = b;
    return __builtin_amdgcn_perm(cb.u + 0x8000u, ca.u + 0x8000u, 0x07060302u);
}

// pack 2 f32 -> 2 bf16, truncating (P-matrix: positive values, <=0.2% bias)
__device__ inline unsigned int pk_bf2t(float a, float b) {
    union { float f; unsigned int u; } ca, cb; ca.f = a; cb.f = b;
    return __builtin_amdgcn_perm(cb.u, ca.u, 0x07060302u);
}

// ---------------- fp32 -> bf16 pre-convert ----------------
__global__ __launch_bounds__(256) void convert_kernel(
    const float* __restrict__ x, const float* __restrict__ Wq,
    const float* __restrict__ Wk, const float* __restrict__ Wv,
    const float* __restrict__ Wo, unsigned short* __restrict__ xb,
    unsigned short* __restrict__ wb)
{
    const size_t i8 = ((size_t)blockIdx.x * 256 + threadIdx.x) * 8;
    const float* src; unsigned short* dst;
    if (i8 < (size_t)MROWS * EMB) { src = x + i8; dst = xb + i8; }
    else {
        size_t j = i8 - (size_t)MROWS * EMB;
        int w = (int)(j >> 18); size_t off = j & 262143;
        src = (w == 0 ? Wq : w == 1 ? Wk : w == 2 ? Wv : Wo) + off;
        dst = wb + (size_t)w * 262144 + off;
    }
    *(short8*)dst = load8f(src);
}

// ---------------- QKV projection, 128x128, BK=64, dbuf, LDS epilogue ----------------
// z=0 -> Q [b,h,s,d] scaled SC2; z=1 -> K [b,h,s,d]; z=2 -> V^T [b,h,d,s]
__global__ __launch_bounds__(256) void qkv_kernel(
    const unsigned short* __restrict__ xb, const unsigned short* __restrict__ wb,
    const float* __restrict__ bq, const float* __restrict__ bk,
    const float* __restrict__ bv, unsigned short* __restrict__ Qo,
    unsigned short* __restrict__ Ko, unsigned short* __restrict__ VTo)
{
    __shared__ unsigned short smem[32768];  // sA[2][8192] | sB[2][8192]; epilogue ct aliases

    const int tid = threadIdx.x, wave = tid >> 6, lane = tid & 63;
    const int quad = lane >> 4, l16 = lane & 15;
    const int wm = wave >> 1, wn = wave & 1;
    const int row0 = blockIdx.x * 128, col0 = blockIdx.y * 128;
    const int z = blockIdx.z;

    unsigned short* sA = smem;
    unsigned short* sB = smem + 16384;

    const unsigned short* A = xb + (size_t)row0 * EMB;
    const unsigned short* Bm = wb + (size_t)z * 262144 + (size_t)col0 * EMB;
    const float* bias = z == 0 ? bq : z == 1 ? bk : bv;
    unsigned short* out = z == 0 ? Qo : z == 1 ? Ko : VTo;

    auto stage = [&](int buf, int k0) {
#pragma unroll
        for (int it = 0; it < 4; ++it) {
            const int s = it * 256 + tid;
            const int row = s >> 3, cg = (s & 7) ^ (row & 7);
            const size_t go = (size_t)row * EMB + k0 + cg * 8;
            gload_lds16(A + go, &sA[buf * 8192 + (it * 256 + wave * 64) * 8]);
            gload_lds16(Bm + go, &sB[buf * 8192 + (it * 256 + wave * 64) * 8]);
        }
    };

    floatx4 acc[4][4];
#pragma unroll
    for (int i = 0; i < 4; ++i)
#pragma unroll
        for (int j = 0; j < 4; ++j) { floatx4 zz = {0.f,0.f,0.f,0.f}; acc[i][j] = zz; }

    stage(0, 0);
    int buf = 0;
    for (int k0 = 0; k0 < EMB; k0 += 64) {
        __syncthreads();
        if (k0 + 64 < EMB) stage(buf ^ 1, k0 + 64);
#pragma unroll
        for (int kk = 0; kk < 2; ++kk) {
            short8 a[4], b[4];
#pragma unroll
            for (int mi = 0; mi < 4; ++mi)
                a[mi] = *(const short8*)&sA[buf * 8192 + (wm * 64 + mi * 16 + l16) * 64 + (((kk * 4 + quad) ^ (l16 & 7)) << 3)];
#pragma unroll
            for (int ni = 0; ni < 4; ++ni)
                b[ni] = *(const short8*)&sB[buf * 8192 + (wn * 64 + ni * 16 + l16) * 64 + (((kk * 4 + quad) ^ (l16 & 7)) << 3)];
            if (z != 2) {
                // swapped operands -> acc[i][j] = C^T block: rows n (i), cols m (j)
#pragma unroll
                for (int i = 0; i < 4; ++i)
#pragma unroll
                    for (int j = 0; j < 4; ++j)
                        acc[i][j] = __builtin_amdgcn_mfma_f32_16x16x32_bf16(b[i], a[j], acc[i][j], 0, 0, 0);
            } else {
#pragma unroll
                for (int i = 0; i < 4; ++i)
#pragma unroll
                    for (int j = 0; j < 4; ++j)
                        acc[i][j] = __builtin_amdgcn_mfma_f32_16x16x32_bf16(a[i], b[j], acc[i][j], 0, 0, 0);
            }
        }
        buf ^= 1;
    }

    // ---- epilogue: pack b64 into ct[row][132] then coalesced b128 stores ----
    __syncthreads();
    unsigned short* ct = smem;  // 128 x 132 shorts = 33.8 KB (aliases staging)
    const float qs = (z == 0) ? SC2 : 1.0f;
    if (z != 2) {
#pragma unroll
        for (int i = 0; i < 4; ++i) {
            const int n0 = wn * 64 + i * 16 + quad * 4;
            const float4 fb = *(const float4*)&bias[col0 + n0];
#pragma unroll
            for (int j = 0; j < 4; ++j) {
                const int m = wm * 64 + j * 16 + l16;
                ushort4 pk;
                pk.x = f2bf_rne((acc[i][j][0] + fb.x) * qs);
                pk.y = f2bf_rne((acc[i][j][1] + fb.y) * qs);
                pk.z = f2bf_rne((acc[i][j][2] + fb.z) * qs);
                pk.w = f2bf_rne((acc[i][j][3] + fb.w) * qs);
                *(ushort4*)&ct[m * 132 + n0] = pk;
            }
        }
    } else {
#pragma unroll
        for (int j = 0; j < 4; ++j) {
            const int n = wn * 64 + j * 16 + l16;
            const float fb = bias[col0 + n];
#pragma unroll
            for (int i = 0; i < 4; ++i) {
                const int m0 = wm * 64 + i * 16 + quad * 4;
                ushort4 pk;
                pk.x = f2bf_rne(acc[i][j][0] + fb);
                pk.y = f2bf_rne(acc[i][j][1] + fb);
                pk.z = f2bf_rne(acc[i][j][2] + fb);
                pk.w = f2bf_rne(acc[i][j][3] + fb);
                *(ushort4*)&ct[n * 132 + m0] = pk;
            }
        }
    }
    __syncthreads();
#pragma unroll
    for (int it = 0; it < 8; ++it) {
        const int idx = it * 256 + tid;
        const int row = idx >> 4, chunk = idx & 15;
        short8 v = *(const short8*)&ct[row * 132 + chunk * 8];
        size_t addr;
        if (z != 2) {
            const int m_g = row0 + row;
            const int b = m_g >> 12, s = m_g & 4095;
            const int n_g = col0 + chunk * 8;
            const int h = n_g >> 6, d = n_g & 63;
            addr = ((size_t)((b * NH + h) * SEQ + s)) * HD + d;
        } else {
            const int n_g = col0 + row;
            const int h = n_g >> 6, d = n_g & 63;
            const int m_g = row0 + chunk * 8;
            const int b = m_g >> 12, s0 = m_g & 4095;
            addr = ((size_t)((b * NH + h) * HD + d)) * SEQ + s0;
        }
        *(short8*)&out[addr] = v;
    }
}

// ---------------- flash attention: 2q-group x 2t-half waves, W_q=64, K=32 PV ----------------
// grid (bh, q-tile): same-bh blocks land on same XCD (stride 16 % 8 == 0) -> L2 reuse
__global__ __launch_bounds__(256, 2) void attn_kernel(
    const unsigned short* __restrict__ Q, const unsigned short* __restrict__ K,
    const unsigned short* __restrict__ VT, unsigned short* __restrict__ Oout)
{
    // staging: sK[buf][4096] @ 0, sVT[buf][4096] @ 8192 (shorts). 32 KB.
    // epilogue aliases as float[8192]: [wq][ (mi*4+dt)*256 + (quad*4+r)*16 + l16 ]
    __shared__ unsigned short smem[16384];
    __shared__ float sPS2[128];  // [wq][64] psum partials from wt=1 waves

    const int tid = threadIdx.x, wave = tid >> 6, lane = tid & 63;
    const int quad = lane >> 4, l16 = lane & 15;
    const int wq = wave >> 1, wt = wave & 1;
    const int bh = blockIdx.x, q0 = blockIdx.y * 128;
    const int xm = l16 & 7;

    const unsigned short* Qh = Q + (size_t)bh * SEQ * HD;
    const unsigned short* Kh = K + (size_t)bh * SEQ * HD;
    const unsigned short* Vh = VT + (size_t)bh * HD * SEQ;

    // this wave's 64 q-rows (q-group wq), mi = 0..3
    short8 qf[4][2];  // [mi][kk]
#pragma unroll
    for (int mi = 0; mi < 4; ++mi)
#pragma unroll
        for (int kk = 0; kk < 2; ++kk)
            qf[mi][kk] = *(const short8*)(Qh + (size_t)(q0 + wq * 64 + mi * 16 + l16) * HD + kk * 32 + quad * 8);

    // permuted K-row map for this wave's 32-t half (wt): tile T, A-row m ->
    // t = wt*32 + 8*(m>>2) + 4*T + (m&3); output rows (quad,r) hold
    // t = wt*32 + 8*quad + 4*T + r -> (T0,T1) pair = 16x16x32 A-frag.
    int kbase[2], kx0[2], kx1[2];
#pragma unroll
    for (int T = 0; T < 2; ++T) {
        const int R = wt * 32 + ((l16 >> 2) << 3) + (T << 2) + (l16 & 3);
        const int fR = (R & 7) ^ ((R >> 2) & 7);  // matches staging swizzle fK
        kbase[T] = R * 64;
        kx0[T] = (quad ^ fR) << 3;
        kx1[T] = ((4 + quad) ^ fR) << 3;
    }

    floatx4 oacc[4][4];  // [mi][dt] partial O over this wave's t-half
#pragma unroll
    for (int mi = 0; mi < 4; ++mi)
#pragma unroll
        for (int dt = 0; dt < 4; ++dt) { floatx4 zz = {0.f,0.f,0.f,0.f}; oacc[mi][dt] = zz; }
    floatx4 sacc[4];  // psum partial via ones-MFMA (row-sum, replicated over l16)
#pragma unroll
    for (int mi = 0; mi < 4; ++mi) { floatx4 zz = {0.f,0.f,0.f,0.f}; sacc[mi] = zz; }
    const floatx4 z4 = {0.f, 0.f, 0.f, 0.f};
    const short ob = (short)0x3F80;  // bf16 1.0
    const short8 ones8 = {ob, ob, ob, ob, ob, ob, ob, ob};

    // stage one 64-t tile (K 64x64, V^T 64x64); 256 threads, 2 psi passes (same as R3)
    auto stage = [&](int buf, int t0) {
#pragma unroll
        for (int psi = 0; psi < 2; ++psi) {
            const int r = psi * 32 + wave * 8 + (lane >> 3);
            const int j = lane & 7;
            const int cK = j ^ ((r & 7) ^ ((r >> 2) & 7));  // fK swizzle
            const int cV = j ^ (r & 7);
            gload_lds16(Kh + (size_t)(t0 + r) * HD + cK * 8,
                        &smem[buf * 4096 + psi * 2048 + wave * 512]);
            gload_lds16(Vh + (size_t)r * SEQ + t0 + cV * 8,
                        &smem[8192 + buf * 4096 + psi * 2048 + wave * 512]);
        }
    };

    stage(0, 0);
    int buf = 0;
    for (int t0 = 0; t0 < SEQ; t0 += 64) {
        __syncthreads();
        if (t0 + 64 < SEQ) stage(buf ^ 1, t0 + 64);

        const unsigned short* sKs  = &smem[buf * 4096];
        const unsigned short* sVTs = &smem[8192 + buf * 4096];

        // K frags for this wave's 32-t half (4 b128), shared across all 4 mi
        short8 bK0[2], bK1[2];
#pragma unroll
        for (int T = 0; T < 2; ++T) {
            bK0[T] = *(const short8*)&sKs[kbase[T] + kx0[T]];
            bK1[T] = *(const short8*)&sKs[kbase[T] + kx1[T]];
        }
        // V frags for this wave's 32-t half (4 b128), shared across all 4 mi
        short8 bv8[4];
#pragma unroll
        for (int dt = 0; dt < 4; ++dt)
            bv8[dt] = *(const short8*)&sVTs[(dt * 16 + l16) * 64 + (((wt * 4 + quad) ^ xm) << 3)];

#pragma unroll
        for (int mi = 0; mi < 4; ++mi) {
            // S^T = K Q^T (Q pre-scaled, log2-domain); const-zero C on first half
            floatx4 s0 = __builtin_amdgcn_mfma_f32_16x16x32_bf16(bK0[0], qf[mi][0], z4, 0, 0, 0);
            floatx4 s1 = __builtin_amdgcn_mfma_f32_16x16x32_bf16(bK0[1], qf[mi][0], z4, 0, 0, 0);
            s0 = __builtin_amdgcn_mfma_f32_16x16x32_bf16(bK1[0], qf[mi][1], s0, 0, 0, 0);
            s1 = __builtin_amdgcn_mfma_f32_16x16x32_bf16(bK1[1], qf[mi][1], s1, 0, 0, 0);

            // exp2 -> truncating pack; order [T0.r0-3, T1.r0-3] == k = 8*quad+0..7
            const float e0 = __builtin_amdgcn_exp2f(s0[0]);
            const float e1 = __builtin_amdgcn_exp2f(s0[1]);
            const float e2 = __builtin_amdgcn_exp2f(s0[2]);
            const float e3 = __builtin_amdgcn_exp2f(s0[3]);
            const float e4 = __builtin_amdgcn_exp2f(s1[0]);
            const float e5 = __builtin_amdgcn_exp2f(s1[1]);
            const float e6 = __builtin_amdgcn_exp2f(s1[2]);
            const float e7 = __builtin_amdgcn_exp2f(s1[3]);
            union { uint4 u; short8 s; } cv;
            cv.u.x = pk_bf2t(e0, e1);
            cv.u.y = pk_bf2t(e2, e3);
            cv.u.z = pk_bf2t(e4, e5);
            cv.u.w = pk_bf2t(e6, e7);
            const short8 paf = cv.s;

            sacc[mi] = __builtin_amdgcn_mfma_f32_16x16x32_bf16(paf, ones8, sacc[mi], 0, 0, 0);
#pragma unroll
            for (int dt = 0; dt < 4; ++dt)
                oacc[mi][dt] = __builtin_amdgcn_mfma_f32_16x16x32_bf16(paf, bv8[dt], oacc[mi][dt], 0, 0, 0);
        }
        buf ^= 1;
    }

    // ---- cross-wave (wt) reduce: O = O_0 + O_1, psum likewise ----
    __syncthreads();  // all staging reads done; safe to alias smem
    float* sRed = (float*)smem;  // [wq][ (mi*4+dt)*256 + (quad*4+r)*16 + l16 ]
    if (wt == 1) {
#pragma unroll
        for (int mi = 0; mi < 4; ++mi) {
#pragma unroll
            for (int dt = 0; dt < 4; ++dt)
#pragma unroll
                for (int r = 0; r < 4; ++r)
                    sRed[wq * 4096 + (mi * 4 + dt) * 256 + (quad * 4 + r) * 16 + l16] = oacc[mi][dt][r];
            if (l16 == 0) {
#pragma unroll
                for (int r = 0; r < 4; ++r)
                    sPS2[wq * 64 + mi * 16 + quad * 4 + r] = sacc[mi][r];
            }
        }
    }
    __syncthreads();
    if (wt == 0) {
        const int b = bh >> 3, h = bh & 7;
#pragma unroll
        for (int mi = 0; mi < 4; ++mi) {
            float inv[4];
#pragma unroll
            for (int r = 0; r < 4; ++r)
                inv[r] = 1.0f / (sacc[mi][r] + sPS2[wq * 64 + mi * 16 + quad * 4 + r]);
#pragma unroll
            for (int dt = 0; dt < 4; ++dt)
#pragma unroll
                for (int r = 0; r < 4; ++r) {
                    const float o = oacc[mi][dt][r] +
                        sRed[wq * 4096 + (mi * 4 + dt) * 256 + (quad * 4 + r) * 16 + l16];
                    const int s = q0 + wq * 64 + mi * 16 + quad * 4 + r;
                    Oout[((size_t)b * SEQ + s) * EMB + h * HD + dt * 16 + l16] = f2bf_rne(o * inv[r]);
                }
        }
    }
}

// ---------------- output projection, 64x128 tile, double-buffered ----------------
__global__ __launch_bounds__(256) void outproj_kernel(
    const unsigned short* __restrict__ Ain, const unsigned short* __restrict__ wob,
    const float* __restrict__ bias, const float* __restrict__ X,
    float* __restrict__ out)
{
    __shared__ unsigned short sA[2][4096];
    __shared__ unsigned short sB[2][8192];

    const int tid = threadIdx.x, wave = tid >> 6, lane = tid & 63;
    const int quad = lane >> 4, l16 = lane & 15;
    const int wm = wave >> 1, wn = wave & 1;
    const int row0 = blockIdx.x * 64, col0 = blockIdx.y * 128;

    const unsigned short* A = Ain + (size_t)row0 * EMB;
    const unsigned short* Bm = wob + (size_t)col0 * EMB;

    auto stage = [&](int buf, int k0) {
#pragma unroll
        for (int it = 0; it < 2; ++it) {
            const int s = it * 256 + tid;
            const int row = s >> 3, cg = (s & 7) ^ (row & 7);
            gload_lds16(A + (size_t)row * EMB + k0 + cg * 8, &sA[buf][(it * 256 + wave * 64) * 8]);
        }
#pragma unroll
        for (int it = 0; it < 4; ++it) {
            const int s = it * 256 + tid;
            const int row = s >> 3, cg = (s & 7) ^ (row & 7);
            gload_lds16(Bm + (size_t)row * EMB + k0 + cg * 8, &sB[buf][(it * 256 + wave * 64) * 8]);
        }
    };

    floatx4 acc[2][4];
#pragma unroll
    for (int mi = 0; mi < 2; ++mi)
#pragma unroll
        for (int ni = 0; ni < 4; ++ni) { floatx4 zz = {0.f,0.f,0.f,0.f}; acc[mi][ni] = zz; }

    stage(0, 0);
    int buf = 0;
    for (int k0 = 0; k0 < EMB; k0 += 64) {
        __syncthreads();
        if (k0 + 64 < EMB) stage(buf ^ 1, k0 + 64);
#pragma unroll
        for (int kk = 0; kk < 2; ++kk) {
            short8 a[2], b[4];
#pragma unroll
            for (int mi = 0; mi < 2; ++mi)
                a[mi] = *(const short8*)&sA[buf][(wm * 32 + mi * 16 + l16) * 64 + (((kk * 4 + quad) ^ (l16 & 7)) << 3)];
#pragma unroll
            for (int ni = 0; ni < 4; ++ni)
                b[ni] = *(const short8*)&sB[buf][(wn * 64 + ni * 16 + l16) * 64 + (((kk * 4 + quad) ^ (l16 & 7)) << 3)];
#pragma unroll
            for (int mi = 0; mi < 2; ++mi)
#pragma unroll
                for (int ni = 0; ni < 4; ++ni)
                    acc[mi][ni] = __builtin_amdgcn_mfma_f32_16x16x32_bf16(a[mi], b[ni], acc[mi][ni], 0, 0, 0);
        }
        buf ^= 1;
    }

#pragma unroll
    for (int mi = 0; mi < 2; ++mi)
#pragma unroll
        for (int ni = 0; ni < 4; ++ni) {
            const int n = col0 + wn * 64 + ni * 16 + l16;
            const float bs = bias[n];
#pragma unroll
            for (int r = 0; r < 4; ++r) {
                const int m = row0 + wm * 32 + mi * 16 + quad * 4 + r;
                const size_t idx = (size_t)m * EMB + n;
                out[idx] = acc[mi][ni][r] + bs + X[idx];
            }
        }
}

extern "C" void kernel_launch(void* const* d_in, const int* in_sizes, int n_in,
                              void* d_out, int out_size, void* d_ws, size_t ws_size,
                              hipStream_t stream) {
    const float* x  = (const float*)d_in[0];
    const float* Wq = (const float*)d_in[1];
    const float* bq = (const float*)d_in[2];
    const float* Wk = (const float*)d_in[3];
    const float* bk = (const float*)d_in[4];
    const float* Wv = (const float*)d_in[5];
    const float* bv = (const float*)d_in[6];
    const float* Wo = (const float*)d_in[7];
    const float* bo = (const float*)d_in[8];
    float* out = (float*)d_out;

    const size_t SZ = (size_t)MROWS * EMB;
    unsigned short* wsXB = (unsigned short*)d_ws;  // also O (attn output)
    unsigned short* wsWB = wsXB + SZ;
    unsigned short* wsQ  = wsWB + 4 * 262144;
    unsigned short* wsK  = wsQ + SZ;
    unsigned short* wsVT = wsK + SZ;

    convert_kernel<<<2560, 256, 0, stream>>>(x, Wq, Wk, Wv, Wo, wsXB, wsWB);
    qkv_kernel<<<dim3(MROWS / 128, EMB / 128, 3), 256, 0, stream>>>(
        wsXB, wsWB, bq, bk, bv, wsQ, wsK, wsVT);
    attn_kernel<<<dim3(2 * NH, SEQ / 128), 256, 0, stream>>>(wsQ, wsK, wsVT, wsXB);
    outproj_kernel<<<dim3(MROWS / 64, EMB / 128), 256, 0, stream>>>(
        wsXB, wsWB + 3 * 262144, bo, x, out);
}